// Round 9
// baseline (198.815 us; speedup 1.0000x reference)
//
#include <hip/hip_runtime.h>

// Inverse SWT (db4, 3 levels), T=4096, circular boundary.
// v8: v7's cross-row DMA pipeline with the vmcnt-ordering bug fixed.
// v7 post-mortem: it issued next-row DMA BEFORE the current row's cD2/cD1
// register loads; vmcnt retires in order, so the compiler's use-wait for d2
// could only be satisfied by first retiring the next-row DMA -> every row's
// level-2 compute blocked on 32 KB of next-row HBM staging (tighter
// serialization than v5, hence the regression). Fix: issue d2/d1 FIRST,
// then the DMA (order pinned by sched_barrier(0)); now d2's use-wait is
// vmcnt(8) and d1's vmcnt(4), leaving the next-row DMA in flight under the
// whole compute phase. Counted barriers re-derived: VMC = 14,18,18,14.
// Per-level math identical to verified v5/v7 -> bit-identical output.

namespace {

constexpr int TT = 4096;       // time length (floats)
constexpr int T4 = TT / 4;     // float4 chunks per row
constexpr int NT = 512;        // threads per block (8 waves)
constexpr int R  = 4;          // rows per block

constexpr float LO[8] = {
    0.23037781330885523f,  0.7148465705525415f,  0.6308807679295904f,
    -0.02798376941698385f, -0.18703481171888114f, 0.030841381835986965f,
    0.032883011666982945f, -0.010597401784997278f};
constexpr float HI[8] = {
    -0.010597401784997278f, -0.032883011666982945f, 0.030841381835986965f,
    0.18703481171888114f,   -0.02798376941698385f,  -0.6308807679295904f,
    0.7148465705525415f,    -0.23037781330885523f};

// Async 16B global->LDS DMA (LDS dest wave-uniform base + lane*16).
#define GLD16(gp, lp)                                                      \
  __builtin_amdgcn_global_load_lds(                                        \
      (const __attribute__((address_space(1))) void*)(gp),                 \
      (__attribute__((address_space(3))) void*)(lp), 16, 0, 0)

// XOR slot swizzle (involution within 64-chunk groups): spreads the
// lane-stride-2-chunk b128 window reads across banks.
__device__ __forceinline__ int sl(int c) {
  c &= (T4 - 1);
  return c ^ ((c >> 3) & 7);
}

template <int W4>
__device__ __forceinline__ void lds_window(const float4* b, int c0, float* w) {
#pragma unroll
  for (int i = 0; i < W4; ++i) {
    const float4 v = b[sl(c0 + i)];
    w[4 * i + 0] = v.x; w[4 * i + 1] = v.y;
    w[4 * i + 2] = v.z; w[4 * i + 3] = v.w;
  }
}

template <int NC>
__device__ __forceinline__ void reg_window(const float4* d, float* w) {
#pragma unroll
  for (int i = 0; i < NC; ++i) {
    w[4 * i + 0] = d[i].x; w[4 * i + 1] = d[i].y;
    w[4 * i + 2] = d[i].z; w[4 * i + 3] = d[i].w;
  }
}

// acc[jc][r] += sum_m c[m] * w[D*(7-m) + 4*jc + r]  (v5's exact FMA order)
template <int D>
__device__ __forceinline__ void accum(const float* c, const float* w,
                                      float a[2][4]) {
#pragma unroll
  for (int m = 0; m < 8; ++m) {
    const int o = D * (7 - m);
#pragma unroll
    for (int jc = 0; jc < 2; ++jc)
#pragma unroll
      for (int r = 0; r < 4; ++r) a[jc][r] += c[m] * w[o + 4 * jc + r];
  }
}

// One row. VMC = counted vmcnt at the staging barrier (exact; derived from
// in-order retirement with the d2/d1-before-DMA issue order — see caller).
template <int VMC, bool PREF>
__device__ __forceinline__ void do_row(const float* xrow, const float* xnext,
                                       float* Pc, float* Qc, float* Pn,
                                       float* Qn, float* outrow, int t) {
  const float4* P4 = reinterpret_cast<const float4*>(Pc);
  const float4* Q4 = reinterpret_cast<const float4*>(Qc);
  float4* Pw = reinterpret_cast<float4*>(Pc);

  // b0: all waves done reading Pn/Qn (their previous-row contents) -> safe
  // to DMA-fill them below.
  asm volatile("s_waitcnt lgkmcnt(0)\n\ts_barrier" ::: "memory");

  // (1) THIS row's cD2/cD1 register windows, issued BEFORE the next-row DMA
  // so their compiler-inserted use-waits (vmcnt 8 / 4) leave the DMA in
  // flight (in-order retirement: waiting on op X retires everything older).
  const float4* g2 = reinterpret_cast<const float4*>(xrow + 2 * TT);
  const float4* g1 = reinterpret_cast<const float4*>(xrow + 3 * TT);
  float4 d2[6], d1[4];
#pragma unroll
  for (int i = 0; i < 6; ++i) d2[i] = g2[(2 * t - 2 + i) & (T4 - 1)];
#pragma unroll
  for (int i = 0; i < 4; ++i) d1[i] = g1[(2 * t - 1 + i) & (T4 - 1)];

  // Pin issue order: d2/d1 loads strictly before the DMA ops.
  __builtin_amdgcn_sched_barrier(0);

  // (2) next row's cA/cD3 DMA — streams under this row's whole compute.
  if constexpr (PREF) {
#pragma unroll
    for (int k = 0; k < 2; ++k) {
      const int s = k * NT + t;
      GLD16(xnext + 0 * TT + sl(s) * 4, Pn + s * 4);
    }
#pragma unroll
    for (int k = 0; k < 2; ++k) {
      const int s = k * NT + t;
      GLD16(xnext + 1 * TT + sl(s) * 4, Qn + s * 4);
    }
  }

  // (3) b1: THIS row's cA/cD3 (issued one row ago) landed in every wave.
  asm volatile("s_waitcnt vmcnt(%0)\n\ts_barrier" ::"n"(VMC) : "memory");

  float w[36];
  float a[2][4] = {{0.f, 0.f, 0.f, 0.f}, {0.f, 0.f, 0.f, 0.f}};

  // ---- level 3 (D=4): res=cA(LDS), hi=cD3(LDS) ----
  lds_window<9>(P4, 2 * t - 4, w);
  accum<4>(LO, w, a);
  lds_window<9>(Q4, 2 * t - 4, w);
  accum<4>(HI, w, a);
  float4 r0 = make_float4(0.5f * a[0][0], 0.5f * a[0][1], 0.5f * a[0][2],
                          0.5f * a[0][3]);
  float4 r1 = make_float4(0.5f * a[1][0], 0.5f * a[1][1], 0.5f * a[1][2],
                          0.5f * a[1][3]);

  asm volatile("s_waitcnt lgkmcnt(0)\n\ts_barrier" ::: "memory");  // b2
  Pw[sl(2 * t)] = r0;
  Pw[sl(2 * t + 1)] = r1;
  asm volatile("s_waitcnt lgkmcnt(0)\n\ts_barrier" ::: "memory");  // b3

  // ---- level 2 (D=2): res(LDS), hi=cD2(regs) ----
#pragma unroll
  for (int jc = 0; jc < 2; ++jc)
#pragma unroll
    for (int r = 0; r < 4; ++r) a[jc][r] = 0.f;
  lds_window<6>(P4, 2 * t - 2, w);
  accum<2>(LO, w, a);
  reg_window<6>(d2, w);
  accum<2>(HI, w, a);
  r0 = make_float4(0.5f * a[0][0], 0.5f * a[0][1], 0.5f * a[0][2],
                   0.5f * a[0][3]);
  r1 = make_float4(0.5f * a[1][0], 0.5f * a[1][1], 0.5f * a[1][2],
                   0.5f * a[1][3]);

  asm volatile("s_waitcnt lgkmcnt(0)\n\ts_barrier" ::: "memory");  // b4
  Pw[sl(2 * t)] = r0;
  Pw[sl(2 * t + 1)] = r1;
  asm volatile("s_waitcnt lgkmcnt(0)\n\ts_barrier" ::: "memory");  // b5

  // ---- level 1 (D=1): res(LDS), hi=cD1(regs); straight to global ----
#pragma unroll
  for (int jc = 0; jc < 2; ++jc)
#pragma unroll
    for (int r = 0; r < 4; ++r) a[jc][r] = 0.f;
  lds_window<4>(P4, 2 * t - 1, w);
  accum<1>(LO, w, a);
  reg_window<4>(d1, w);
  accum<1>(HI, w, a);

  float4* out4 = reinterpret_cast<float4*>(outrow);
  out4[2 * t + 0] = make_float4(0.5f * a[0][0], 0.5f * a[0][1],
                                0.5f * a[0][2], 0.5f * a[0][3]);
  out4[2 * t + 1] = make_float4(0.5f * a[1][0], 0.5f * a[1][1],
                                0.5f * a[1][2], 0.5f * a[1][3]);
}

__global__ __launch_bounds__(NT, 4) void iswt_kernel(const float* __restrict__ x,
                                                     float* __restrict__ out) {
  __shared__ __align__(16) float P0[TT], Q0[TT], P1[TT], Q1[TT];  // 64 KiB

  const int t = threadIdx.x;
  const size_t blk = blockIdx.x;  // handles rows 4*blk .. 4*blk+3

  const float* xg = x + blk * (size_t)(R * 4 * TT);
  float* og = out + blk * (size_t)(R * TT);

  // Prologue: DMA row 0's cA->P0, cD3->Q0 (4 ops).
#pragma unroll
  for (int k = 0; k < 2; ++k) {
    const int s = k * NT + t;
    GLD16(xg + 0 * TT + sl(s) * 4, P0 + s * 4);
  }
#pragma unroll
  for (int k = 0; k < 2; ++k) {
    const int s = k * NT + t;
    GLD16(xg + 1 * TT + sl(s) * 4, Q0 + s * 4);
  }

  // VMC audit (in-order retirement, issue order per row:
  // d2d1(10) -> DMA_next(4) -> [b1] -> compute -> st(4)):
  //  row0: after DMA_r0(prologue): d2d1_r0(10)+DMA_r1(4)          = 14
  //  row1: after DMA_r1: st_r0(4)+d2d1_r1(10)+DMA_r2(4)           = 18
  //  row2: after DMA_r2: st_r1(4)+d2d1_r2(10)+DMA_r3(4)           = 18
  //  row3: after DMA_r3: st_r2(4)+d2d1_r3(10)                     = 14
  do_row<14, true >(xg + 0 * 4 * TT, xg + 1 * 4 * TT, P0, Q0, P1, Q1,
                    og + 0 * TT, t);
  do_row<18, true >(xg + 1 * 4 * TT, xg + 2 * 4 * TT, P1, Q1, P0, Q0,
                    og + 1 * TT, t);
  do_row<18, true >(xg + 2 * 4 * TT, xg + 3 * 4 * TT, P0, Q0, P1, Q1,
                    og + 2 * TT, t);
  do_row<14, false>(xg + 3 * 4 * TT, nullptr,          P1, Q1, P0, Q0,
                    og + 3 * TT, t);
}

}  // namespace

extern "C" void kernel_launch(void* const* d_in, const int* in_sizes, int n_in,
                              void* d_out, int out_size, void* d_ws, size_t ws_size,
                              hipStream_t stream) {
  const float* x = reinterpret_cast<const float*>(d_in[0]);
  float* out = reinterpret_cast<float*>(d_out);
  const int rows = out_size / TT;  // B*N = 2048
  iswt_kernel<<<rows / R, NT, 0, stream>>>(x, out);
}